// Round 1
// 127.788 us; speedup vs baseline: 1.0884x; 1.0884x over previous
//
#include <hip/hip_runtime.h>

// GR4J production-store scan, parallelized by contraction.
//
// Round-9: pair-composed degree-7 polynomial warm-up.
// r8 counters: Occupancy 2.56% (1 wave/CU), VALUBusy 12%, HBM 7% => pure
// dependent-chain latency bound: ~89 cyc/step = 5 VALU levels x ~13 cyc
// lone-wave dep latency + ~23 cyc issue. Warm-up (1408 of 1536 steps) needs
// no outputs, only the end state => compose each pair of steps into ONE
// degree-7 polynomial (Chebyshev collocation at 8 nodes against the exact
// cubic+quintic pair map). Estrin evaluation = 3 dependent levels per pair
// = 1.5 levels/step (was 5), same 16B/step LDS feed (32B/pair).
//   - state kept normalized: sigma = (s-cen)/hw in [-1,1] (well-conditioned
//     f32 DCT -> monomial transform; verified vs T1/T2/T5 identities)
//   - zero-padding pairs (block 0) get ANALYTIC coefficients (fit noise would
//     integrate un-contracted over 704 pairs at s=0)
//   - main steps unchanged (exact stepk_m), L_CHUNK 128->64, re-staged k-tile
//   - 256-thread blocks: coeff build on 4 SIMDs, scan on 128 lanes
// Fallback to the round-1 kernel for odd shapes.

typedef float f32x4 __attribute__((ext_vector_type(4)));

#define LCH      64            // main steps per chunk
#define CPB      128           // chunks per block
#define TPB      256           // threads per block
#define BSTEPS   8192          // LCH*CPB main steps per block
#define WUP      1408          // warm-up steps (proven length, r8)
#define WUPAIR   704           // WUP/2 pairs
#define WST      88            // WUPAIR/8 warm stages
#define NPAIRW   4768          // warm tile pairs = 32*(CPB-1)+WUPAIR
#define NCW      151           // warm tile padded cols (32 rows; 149 used)
#define DASLOT   (32*NCW)      // 4832 f32x4 slots per coeff array
#define NCK      129           // main k tile padded cols (64 rows; 128 used)
#define NMST     8             // main stages = LCH/8

// Chebyshev node values cos((2j+1)pi/16) and DCT constants
#define CC1 0.98078528f
#define CC2 0.92387953f
#define CC3 0.83146961f
#define CC4 0.70710678f
#define CC5 0.55557023f
#define CC6 0.38268343f
#define CC7 0.19509032f

// one exact cubic+quintic step, warm-up flavor (state only)
__device__ __forceinline__ void stepk(float& s, const f32x4 k, float gma) {
    float s2m = s * s;
    float t1  = fmaf(k.y, s, k.x);
    float t2  = fmaf(k.w, s, k.z);
    float s1  = fmaf(s2m, t2, t1);
    float w2  = s1 * s1;
    float q4  = gma * s1;
    float w4  = w2 * w2;
    s = fmaf(-q4, w4, s1);
}

// main flavor: also emit ps (= relu(s1 - s_prev), exact) and pc (= gma*s1^5)
__device__ __forceinline__ void stepk_m(float& s, const f32x4 k, float gma,
                                        float& ps_o, float& pc_o) {
    float sp  = s;
    float s2m = s * s;
    float t1  = fmaf(k.y, s, k.x);
    float t2  = fmaf(k.w, s, k.z);
    float s1  = fmaf(s2m, t2, t1);
    float w2  = s1 * s1;
    float q4  = gma * s1;
    float w4  = w2 * w2;
    s = fmaf(-q4, w4, s1);
    ps_o = fmaxf(s1 - sp, 0.0f);
    pc_o = q4 * w4;
}

struct KC { float inv, x1, x1sq, x1_2, two_x1cu, five_x1sq, four_x1; };

// per-step cubic coefficients (identical numerics to round-8 phase 1)
__device__ __forceinline__ f32x4 mkk(float P, float Ev, const KC c,
                                     float& pn_o, float& en_o) {
    float d  = P - Ev;
    float pn = fmaxf(d, 0.f), en = fmaxf(-d, 0.f);
    float up = pn * c.inv, un = en * c.inv;
    float tp = up * fmaf(up * up, -(1.f/3.f), 1.f);
    float tn = un * fmaf(un * un, -(1.f/3.f), 1.f);
    float al = tp * c.inv, be = tn * c.inv;
    float a2 = al * al,  a3v = a2 * al;
    float b2 = be * be,  b3v = b2 * be;
    float e2 = fmaf(-be, c.x1, 1.f);
    float k0 = tp * c.x1;
    float k1 = 1.f - a2 * c.x1sq - (c.x1_2 * be * e2 + c.two_x1cu * b3v);
    float k2 = (a3v * c.x1sq - al) - (c.x1_2 * b2 - be * e2 - c.five_x1sq * b3v);
    float k3 = a2 + b2 - c.four_x1 * b3v;
    pn_o = pn; en_o = en;
    return (f32x4){k0, k1, k2, k3};
}

__global__ __launch_bounds__(256, 1) void scan_pair(
        const float* __restrict__ x, const float* __restrict__ x1p,
        f32x4* __restrict__ pspc4, f32x4* __restrict__ s4,
        float* __restrict__ partials) {
    __shared__ f32x4 smem[2 * DASLOT];          // 154624 B (union of phases)
    __shared__ float red[32];
    f32x4* const dA = smem;                     // warm pair coeffs d0..d3
    f32x4* const dB = smem + DASLOT;            // warm pair coeffs d4..d7
    f32x4* const tk = smem;                     // main k tile (aliases, after barrier)

    const int tid  = threadIdx.x;
    const int lane = tid & 63;
    const int wid  = tid >> 6;
    const int b    = blockIdx.x;

    const float x1 = x1p[0];
    KC c;
    c.inv = 1.0f / x1; c.x1 = x1; c.x1sq = x1 * x1; c.x1_2 = 2.0f * x1;
    c.two_x1cu = 2.0f * x1 * c.x1sq; c.five_x1sq = 5.0f * c.x1sq;
    c.four_x1 = 4.0f * x1;
    const float gma = 64.0f / (6561.0f * c.x1sq * c.x1sq);   // perc = gma*s1^5
    const float cen = (184.0f / 350.0f) * x1;   // sigma domain center
    const float hw  = (208.0f / 350.0f) * x1;   // sigma domain half-width
    const float ihw = 1.0f / hw;

    float snode[8];
    {
        const float ND[8] = { CC1,  CC3,  CC5,  CC7, -CC7, -CC5, -CC3, -CC1};
        #pragma unroll
        for (int j = 0; j < 8; ++j) snode[j] = fmaf(hw, ND[j], cen);
    }
    // analytic coefficients for zero-input (padding) pairs:
    //   sigma' = sigma - (2*gma/hw)*(hw*sigma+cen)^5   (exact binomial)
    f32x4 padA, padB;
    {
        const float qq = -2.0f * gma * ihw;
        const float c2_ = cen * cen, c3_ = c2_ * cen, c4_ = c2_ * c2_, c5_ = c4_ * cen;
        const float h2 = hw * hw, h3 = h2 * hw, h4 = h2 * h2, h5 = h4 * hw;
        padA = (f32x4){qq * c5_, fmaf(qq, 5.0f * hw * c4_, 1.0f),
                       qq * 10.0f * h2 * c3_, qq * 10.0f * h3 * c2_};
        padB = (f32x4){qq * 5.0f * h4 * cen, qq * h5, 0.0f, 0.0f};
    }

    // ---- phase 1a: build degree-7 pair-composed maps (all 4 waves) ----
    {
        const f32x4* __restrict__ x4 = (const f32x4*)x;  // one f32x4 == one pair
        const long Bb = (long)b * 4096 - WUPAIR;
        const f32x4 z4 = (f32x4){0.f, 0.f, 0.f, 0.f};
        long g0 = Bb + tid;
        f32x4 w = (tid < NPAIRW && g0 >= 0) ? x4[g0] : z4;
        #pragma unroll 1
        for (int m = 0; m < 19; ++m) {
            const int p  = tid + (m << 8);
            const int p2 = p + 256;
            const long g  = Bb + p;
            const long g2 = Bb + p2;
            f32x4 wn = (p2 < NPAIRW && g2 >= 0) ? x4[g2] : z4;   // prefetch
            if (p < NPAIRW) {
                f32x4 ra, rb;
                if (g < 0) { ra = padA; rb = padB; }
                else {
                    float du0, du1;
                    const f32x4 kA = mkk(w.x, w.y, c, du0, du1);
                    const f32x4 kB = mkk(w.z, w.w, c, du0, du1);
                    float v[8];
                    #pragma unroll
                    for (int j = 0; j < 8; ++j) {      // 8 independent node evals
                        float s = snode[j];
                        stepk(s, kA, gma);
                        stepk(s, kB, gma);
                        v[j] = (s - cen) * ihw;
                    }
                    const float e0 = v[0] + v[7], e1 = v[1] + v[6];
                    const float e2 = v[2] + v[5], e3 = v[3] + v[4];
                    const float o0 = v[0] - v[7], o1 = v[1] - v[6];
                    const float o2 = v[2] - v[5], o3 = v[3] - v[4];
                    const float a0 = 0.125f * (e0 + e1 + e2 + e3);
                    const float a1 = 0.25f * (o0*CC1 + o1*CC3 + o2*CC5 + o3*CC7);
                    const float a2 = 0.25f * ((e0 - e3)*CC2 + (e1 - e2)*CC6);
                    const float a3 = 0.25f * (o0*CC3 - o1*CC7 - o2*CC1 - o3*CC5);
                    const float a4 = 0.25f * CC4 * ((e0 + e3) - (e1 + e2));
                    const float a5 = 0.25f * (o0*CC5 - o1*CC1 + o2*CC7 + o3*CC3);
                    const float a6 = 0.25f * ((e0 - e3)*CC6 - (e1 - e2)*CC2);
                    const float a7 = 0.25f * (o0*CC7 - o1*CC5 + o2*CC3 - o3*CC1);
                    ra = (f32x4){a0 - a2 + a4 - a6,
                                 a1 - 3.0f*a3 + 5.0f*a5 - 7.0f*a7,
                                 2.0f*a2 - 8.0f*a4 + 18.0f*a6,
                                 4.0f*a3 - 20.0f*a5 + 56.0f*a7};
                    rb = (f32x4){8.0f*a4 - 48.0f*a6,
                                 16.0f*a5 - 112.0f*a7,
                                 32.0f*a6,
                                 64.0f*a7};
                }
                const int slot = (p & 31) * NCW + (p >> 5);
                dA[slot] = ra;
                dB[slot] = rb;
            }
            w = wn;
        }
    }
    __syncthreads();

    // ---- phase 2a: warm-up sigma-scan, 3 dep levels per PAIR (lanes < 128) --
    float aps = 0.f, apc = 0.f, qps = 0.f, qpc = 0.f;
    float sg = 0.f;
    if (tid < CPB) {
        const int l = tid;
        const long chk = (long)b * CPB + l;
        const float s0 = (chk * LCH >= WUP) ? 0.47f * x1 : 0.0f;
        sg = (s0 - cen) * ihw;
        f32x4 PA[8], PB[8], QA[8], QB[8];
        auto rdw = [&](f32x4 (&A)[8], f32x4 (&B)[8], const int st) {
            const int jb = st << 3;                       // pair tile p = 32*l + jb+u
            const int base = (jb & 31) * NCW + l + (jb >> 5);
            #pragma unroll
            for (int u = 0; u < 8; ++u) A[u] = dA[base + u * NCW];
            #pragma unroll
            for (int u = 0; u < 8; ++u) B[u] = dB[base + u * NCW];
        };
        auto wstp = [&](f32x4 (&A)[8], f32x4 (&B)[8]) {
            #pragma unroll
            for (int u = 0; u < 8; ++u) {                 // Estrin deg-7: 3 levels
                const float s2  = sg * sg;
                const float p0  = fmaf(A[u].y, sg, A[u].x);
                const float p1  = fmaf(A[u].w, sg, A[u].z);
                const float p2  = fmaf(B[u].y, sg, B[u].x);
                const float p3  = fmaf(B[u].w, sg, B[u].z);
                const float s4v = s2 * s2;
                const float q0  = fmaf(p1, s2, p0);
                const float q1  = fmaf(p3, s2, p2);
                sg = fmaf(q1, s4v, q0);
            }
        };
        rdw(PA, PB, 0);
        #pragma unroll 1
        for (int st = 0; st < WST; st += 2) {
            rdw(QA, QB, st + 1);
            wstp(PA, PB);
            rdw(PA, PB, st + 2);          // st+2 == WST on last iter: dead in-bounds read
            wstp(QA, QB);
        }
    }
    const float s_after = fmaf(hw, sg, cen);
    __syncthreads();

    // ---- phase 1b: re-stage exact main-step k's (all threads) + pn/en stats -
    float spn = 0.f, sen = 0.f, qpn = 0.f, qen = 0.f;
    {
        const f32x4* __restrict__ x4 = (const f32x4*)x;
        const long Fb = (long)b * 4096;
        f32x4 w = x4[Fb + tid];
        #pragma unroll 1
        for (int m = 0; m < 16; ++m) {
            const int f = tid + (m << 8);
            f32x4 wn = (m < 15) ? x4[Fb + f + 256] : w;   // prefetch
            #pragma unroll
            for (int h = 0; h < 2; ++h) {
                float pn, en;
                const f32x4 k = mkk(h ? w.z : w.x, h ? w.w : w.y, c, pn, en);
                const int t = 2 * f + h;
                tk[(t & 63) * NCK + (t >> 6)] = k;
                spn += pn; sen += en;
                qpn = fmaf(pn, pn, qpn); qen = fmaf(en, en, qen);
            }
            w = wn;
        }
    }
    __syncthreads();

    // ---- phase 2b: exact main scan with outputs (lanes < 128) ----
    if (tid < CPB) {
        const int l = tid;
        const size_t chunk = (size_t)b * CPB + l;
        float s = s_after;
        f32x4 KP[8], KQ[8];
        auto rdk = [&](f32x4 (&K)[8], const int m) {
            const int base = (m << 3) * NCK + l;
            #pragma unroll
            for (int u = 0; u < 8; ++u) K[u] = tk[base + u * NCK];
        };
        auto mst = [&](f32x4 (&K)[8], const int m) {
            float psv[8], pcv[8], sv[8];
            #pragma unroll
            for (int u = 0; u < 8; ++u) {
                stepk_m(s, K[u], gma, psv[u], pcv[u]);
                sv[u] = s;
            }
            #pragma unroll
            for (int u = 0; u < 8; ++u) {
                aps += psv[u]; apc += pcv[u];
                qps = fmaf(psv[u], psv[u], qps); qpc = fmaf(pcv[u], pcv[u], qpc);
            }
            const size_t pb = chunk * 32 + 4 * m;
            pspc4[pb + 0] = (f32x4){psv[0], pcv[0], psv[1], pcv[1]};
            pspc4[pb + 1] = (f32x4){psv[2], pcv[2], psv[3], pcv[3]};
            pspc4[pb + 2] = (f32x4){psv[4], pcv[4], psv[5], pcv[5]};
            pspc4[pb + 3] = (f32x4){psv[6], pcv[6], psv[7], pcv[7]};
            const size_t sb = chunk * 16 + 2 * m;
            s4[sb]     = (f32x4){sv[0], sv[1], sv[2], sv[3]};
            s4[sb + 1] = (f32x4){sv[4], sv[5], sv[6], sv[7]};
        };
        rdk(KP, 0);
        #pragma unroll 1
        for (int m = 0; m < NMST; m += 2) {
            rdk(KQ, m + 1);
            mst(KP, m);
            rdk(KP, m + 2 < NMST ? m + 2 : NMST - 1);     // clamped dead read
            mst(KQ, m + 1);
        }
    }

    // ---- block reduction of 8 stat accumulators ----
    float vals[8] = {spn, sen, aps, apc, qpn, qen, qps, qpc};
    #pragma unroll
    for (int k = 0; k < 8; ++k) {
        float v = vals[k];
        #pragma unroll
        for (int off = 32; off > 0; off >>= 1) v += __shfl_down(v, off, 64);
        if (lane == 0) red[k * 4 + wid] = v;
    }
    __syncthreads();
    if (tid < 8)
        partials[b * 8 + tid] =
            red[tid * 4] + red[tid * 4 + 1] + red[tid * 4 + 2] + red[tid * 4 + 3];
}

// ---- stats finalize folded in + fused normalize/assemble (unchanged) ----
__global__ __launch_bounds__(256) void normalize_stats(
        const float* __restrict__ x, const f32x4* __restrict__ pspc4,
        const float* __restrict__ pA, f32x4* __restrict__ out4,
        int nA, int Thalf, int T) {
    __shared__ float red[256];
    __shared__ float sst[8];
    const int tid = threadIdx.x;
    {   // components: 0 pn,1 en,2 ps,3 pc (sums); 4..7 squares
        const int c = tid & 7;
        float v = 0.f;
        for (int i = tid >> 3; i < nA; i += 32) v += pA[i * 8 + c];
        red[tid] = v;
        __syncthreads();
        for (int off = 128; off >= 8; off >>= 1) {
            if (tid < off) red[tid] += red[tid + off];
            __syncthreads();
        }
        if (tid == 0) {
            const float invT = 1.0f / (float)T;
            #pragma unroll
            for (int k = 0; k < 4; ++k) {
                float mu  = red[k] * invT;
                float var = fmaxf(fmaf(-mu, mu, red[4 + k] * invT), 0.0f);
                sst[k]     = mu;
                sst[4 + k] = (var > 0.0f) ? rsqrtf(var) : 0.0f;
            }
        }
        __syncthreads();
    }
    const float mu0 = sst[0], mu1 = sst[1], mu2 = sst[2], mu3 = sst[3];
    const float is0 = sst[4], is1 = sst[5], is2 = sst[6], is3 = sst[7];
    const f32x4* __restrict__ x4 = (const f32x4*)x;
    for (int i = blockIdx.x * 256 + tid; i < Thalf; i += 1024 * 256) {
        f32x4 xv = x4[i];
        f32x4 pq = pspc4[i];
        float d0 = xv.x - xv.y, d1 = xv.z - xv.w;
        out4[2 * i]     = (f32x4){(fmaxf(d0, 0.f) - mu0) * is0,
                                  (fmaxf(-d0, 0.f) - mu1) * is1,
                                  (pq.x - mu2) * is2,
                                  (pq.y - mu3) * is3};
        out4[2 * i + 1] = (f32x4){(fmaxf(d1, 0.f) - mu0) * is0,
                                  (fmaxf(-d1, 0.f) - mu1) * is1,
                                  (pq.z - mu2) * is2,
                                  (pq.w - mu3) * is3};
    }
}

// ---------------- round-1 fallback (proven; own WARMUP=2048, s0=0) ----------
#define L_CHUNK  128
#define FB_WARMUP 2048
__device__ __forceinline__ float inv1p_fb(float a) {
    float i1 = 1.0f - a;
    float i2 = fmaf(-a, i1, 1.0f);
    return fmaf(-a, i2, 1.0f);
}
struct SCfb { float x1, inv_x1, c49; };
__device__ __forceinline__ void scan_step_fb(float& s, float P, float E, const SCfb c,
                                             float& pn, float& en, float& ps, float& pc) {
    float d = P - E;
    float pn_ = fmaxf(d, 0.0f), en_ = fmaxf(-d, 0.0f);
    float up = pn_ * c.inv_x1;
    float tp = up * fmaf(up * up, -(1.0f / 3.0f), 1.0f);
    float un = en_ * c.inv_x1;
    float tn = un * fmaf(un * un, -(1.0f / 3.0f), 1.0f);
    float r = s * c.inv_x1;
    float ps_ = (tp * c.x1) * fmaf(-r, r, 1.0f) * inv1p_fb(r * tp);
    float es_ = (s * (2.0f - r)) * tn * inv1p_fb((1.0f - r) * tn);
    float s1 = s + ps_ - es_;
    float z = s1 * c.c49, z2 = z * z, v = z2 * z2;
    float t = fmaf(v, fmaf(v, 0.15625f, -0.25f), 1.0f);
    float s2 = s1 * t;
    pn = pn_; en = en_; ps = ps_; pc = s1 - s2; s = s2;
}
__global__ __launch_bounds__(256) void scan_kernel_fb(
        const float* __restrict__ x, const float* __restrict__ x1ptr,
        float* __restrict__ out, float* __restrict__ s_store,
        float* __restrict__ partials, int T) {
    const int c = blockIdx.x * blockDim.x + threadIdx.x;
    const int nchunks = (T + L_CHUNK - 1) / L_CHUNK;
    SCfb cc; cc.x1 = x1ptr[0]; cc.inv_x1 = 1.0f / cc.x1; cc.c49 = (4.0f / 9.0f) * cc.inv_x1;
    float s1a[4] = {0.f, 0.f, 0.f, 0.f};
    float s2a[4] = {0.f, 0.f, 0.f, 0.f};
    if (c < nchunks) {
        const int g0 = c * L_CHUNK;
        const int g1 = min(g0 + L_CHUNK, T);
        const int w0 = max(g0 - FB_WARMUP, 0);
        float s = 0.0f; float pn, en, ps, pc;
        const float2* __restrict__ x2 = (const float2*)x;
        for (int t = w0; t < g0; ++t) { float2 xv = x2[t]; scan_step_fb(s, xv.x, xv.y, cc, pn, en, ps, pc); }
        float4* __restrict__ out4 = (float4*)out;
        for (int t = g0; t < g1; ++t) {
            float2 xv = x2[t];
            scan_step_fb(s, xv.x, xv.y, cc, pn, en, ps, pc);
            out4[t] = make_float4(pn, en, ps, pc);
            s_store[t] = s;
            s1a[0] += pn; s1a[1] += en; s1a[2] += ps; s1a[3] += pc;
            s2a[0] = fmaf(pn, pn, s2a[0]); s2a[1] = fmaf(en, en, s2a[1]);
            s2a[2] = fmaf(ps, ps, s2a[2]); s2a[3] = fmaf(pc, pc, s2a[3]);
        }
    }
    __shared__ float red[256];
    float vals[8] = {s1a[0], s1a[1], s1a[2], s1a[3], s2a[0], s2a[1], s2a[2], s2a[3]};
    for (int k = 0; k < 8; ++k) {
        red[threadIdx.x] = vals[k];
        __syncthreads();
        for (int off = 128; off > 0; off >>= 1) {
            if ((int)threadIdx.x < off) red[threadIdx.x] += red[threadIdx.x + off];
            __syncthreads();
        }
        if (threadIdx.x == 0) partials[blockIdx.x * 8 + k] = red[0];
        __syncthreads();
    }
}
__global__ __launch_bounds__(64) void finalize_fb(
        const float* __restrict__ partials, float* __restrict__ stats, int nblk, int T) {
    const int lane = threadIdx.x;
    float v[8] = {0.f, 0.f, 0.f, 0.f, 0.f, 0.f, 0.f, 0.f};
    for (int b = lane; b < nblk; b += 64)
        for (int k = 0; k < 8; ++k) v[k] += partials[b * 8 + k];
    #pragma unroll
    for (int k = 0; k < 8; ++k)
        for (int off = 32; off > 0; off >>= 1) v[k] += __shfl_down(v[k], off, 64);
    if (lane == 0) {
        const float invT = 1.0f / (float)T;
        for (int k = 0; k < 4; ++k) {
            float mu = v[k] * invT;
            float var = fmaxf(fmaf(-mu, mu, v[k + 4] * invT), 0.0f);
            stats[k] = mu;
            stats[4 + k] = (var > 0.0f) ? rsqrtf(var) : 0.0f;
        }
    }
}
__global__ __launch_bounds__(256) void normalize_fb(
        float* __restrict__ out, const float* __restrict__ stats, int T) {
    const int t = blockIdx.x * blockDim.x + threadIdx.x;
    if (t >= T) return;
    const float4 mu = *(const float4*)stats;
    const float4 is = *(const float4*)(stats + 4);
    float4* o4 = (float4*)out;
    float4 v = o4[t];
    v.x = (v.x - mu.x) * is.x; v.y = (v.y - mu.y) * is.y;
    v.z = (v.z - mu.z) * is.z; v.w = (v.w - mu.w) * is.w;
    o4[t] = v;
}
// -----------------------------------------------------------------------------

extern "C" void kernel_launch(void* const* d_in, const int* in_sizes, int n_in,
                              void* d_out, int out_size, void* d_ws, size_t ws_size,
                              hipStream_t stream) {
    const float* x  = (const float*)d_in[0];
    const float* x1 = (const float*)d_in[1];
    const int T = in_sizes[0] / 2;

    float* out     = (float*)d_out;                // (T,4)
    float* s_store = out + 4 * (size_t)T;          // (T,)

    const int nblk = T / BSTEPS;                   // scan blocks (fast path)

    float* pA = (float*)d_ws;                      // nblk*8 floats (<=2048)
    const size_t pq_off = 2048;                    // f32x4-aligned float offset
    const size_t need = (pq_off + 2 * (size_t)T) * sizeof(float);

    const bool fast = (T % BSTEPS == 0) && nblk >= 1 && nblk <= 256 &&
                      (ws_size >= need);

    if (fast) {
        f32x4* pspc4 = (f32x4*)((float*)d_ws + pq_off);
        scan_pair<<<nblk, TPB, 0, stream>>>(x, x1, pspc4, (f32x4*)s_store, pA);
        normalize_stats<<<1024, 256, 0, stream>>>(x, pspc4, pA,
                                                  (f32x4*)out, nblk, T / 2, T);
    } else {
        float* stats    = (float*)d_ws;
        float* partials = stats + 8;
        const int nchunks = (T + L_CHUNK - 1) / L_CHUNK;
        const int nblkA = (nchunks + 255) / 256;
        scan_kernel_fb<<<nblkA, 256, 0, stream>>>(x, x1, out, s_store, partials, T);
        finalize_fb<<<1, 64, 0, stream>>>(partials, stats, nblkA, T);
        normalize_fb<<<(T + 255) / 256, 256, 0, stream>>>(out, stats, T);
    }
}

// Round 2
// 110.817 us; speedup vs baseline: 1.2551x; 1.1532x over previous
//
#include <hip/hip_runtime.h>

// GR4J production-store scan, parallelized by contraction.
//
// Round-10: OCT-composed (8-step) degree-7 polynomial warm-up, built DIRECTLY
// from x (no intermediate pair maps).
// r9 post-mortem: pair maps cut the chain 3.2x but scan only fell 61->52us.
// Counters (VALUBusy 26%, Occ 9.4%) + arithmetic: remaining cost is
// stage-count-proportional: warm feed = 88 stages x 16 ds_read_b128 x 2 waves
// = 2.88MB LDS (~9.4us pipe) + build ~4-8us + chain 2112 lvls (~10-20us).
// Composition doubling halves chain AND feed AND stages while direct build
// keeps phase-1 ~constant (2x cost per map, half the maps). So: 8-step maps.
//   - warm chain: 176 octs x 3 Estrin levels = 528 levels (was 2112)
//   - warm feed: 22 stages x 16 b128 = 0.72MB (was 2.88MB)
//   - build: 1192 octs x (8 mkk + 64 stepk + DCT) ~ same 3.5us as r9 1a
//   - fit-error amplification Sum(lam^k) ~ 22 (pairs: 83) => oct fit can be
//     15x pair fit error before exceeding r9's accuracy impact
//   - pad octs analytic: sigma' = sigma - 8*gma*(hw*sigma+cen)^5 (O(gma^2))
//   - main steps unchanged (exact stepk_m), LDS 155->132KB
// Fallback to the round-1 kernel for odd shapes.

typedef float f32x4 __attribute__((ext_vector_type(4)));

#define LCH      64            // main steps per chunk
#define CPB      128           // chunks per block
#define TPB      256           // threads per block
#define BSTEPS   8192          // LCH*CPB main steps per block
#define WUP      1408          // warm-up steps (proven length, r8)
#define WUOCT    176           // WUP/8 octs
#define WSTO     22            // WUOCT/8 warm stages
#define NOCTW    1192          // warm tile octs = 8*(CPB-1)+WUOCT
#define NCO      151           // warm tile padded cols (8 rows; 149 used)
#define OASLOT   (8*NCO)       // 1208 f32x4 slots per oct coeff array
#define NCK      129           // main k tile padded cols (64 rows; 128 used)
#define NMST     8             // main stages = LCH/8

// Chebyshev node values cos((2j+1)pi/16) and DCT constants
#define CC1 0.98078528f
#define CC2 0.92387953f
#define CC3 0.83146961f
#define CC4 0.70710678f
#define CC5 0.55557023f
#define CC6 0.38268343f
#define CC7 0.19509032f

// one exact cubic+quintic step, warm-up flavor (state only)
__device__ __forceinline__ void stepk(float& s, const f32x4 k, float gma) {
    float s2m = s * s;
    float t1  = fmaf(k.y, s, k.x);
    float t2  = fmaf(k.w, s, k.z);
    float s1  = fmaf(s2m, t2, t1);
    float w2  = s1 * s1;
    float q4  = gma * s1;
    float w4  = w2 * w2;
    s = fmaf(-q4, w4, s1);
}

// main flavor: also emit ps (= relu(s1 - s_prev), exact) and pc (= gma*s1^5)
__device__ __forceinline__ void stepk_m(float& s, const f32x4 k, float gma,
                                        float& ps_o, float& pc_o) {
    float sp  = s;
    float s2m = s * s;
    float t1  = fmaf(k.y, s, k.x);
    float t2  = fmaf(k.w, s, k.z);
    float s1  = fmaf(s2m, t2, t1);
    float w2  = s1 * s1;
    float q4  = gma * s1;
    float w4  = w2 * w2;
    s = fmaf(-q4, w4, s1);
    ps_o = fmaxf(s1 - sp, 0.0f);
    pc_o = q4 * w4;
}

struct KC { float inv, x1, x1sq, x1_2, two_x1cu, five_x1sq, four_x1; };

// per-step cubic coefficients (identical numerics to round-8 phase 1)
__device__ __forceinline__ f32x4 mkk(float P, float Ev, const KC c,
                                     float& pn_o, float& en_o) {
    float d  = P - Ev;
    float pn = fmaxf(d, 0.f), en = fmaxf(-d, 0.f);
    float up = pn * c.inv, un = en * c.inv;
    float tp = up * fmaf(up * up, -(1.f/3.f), 1.f);
    float tn = un * fmaf(un * un, -(1.f/3.f), 1.f);
    float al = tp * c.inv, be = tn * c.inv;
    float a2 = al * al,  a3v = a2 * al;
    float b2 = be * be,  b3v = b2 * be;
    float e2 = fmaf(-be, c.x1, 1.f);
    float k0 = tp * c.x1;
    float k1 = 1.f - a2 * c.x1sq - (c.x1_2 * be * e2 + c.two_x1cu * b3v);
    float k2 = (a3v * c.x1sq - al) - (c.x1_2 * b2 - be * e2 - c.five_x1sq * b3v);
    float k3 = a2 + b2 - c.four_x1 * b3v;
    pn_o = pn; en_o = en;
    return (f32x4){k0, k1, k2, k3};
}

__global__ __launch_bounds__(256, 1) void scan_oct(
        const float* __restrict__ x, const float* __restrict__ x1p,
        f32x4* __restrict__ pspc4, f32x4* __restrict__ s4,
        float* __restrict__ partials) {
    __shared__ f32x4 smem[64 * NCK];            // 132096 B (union of phases)
    __shared__ float red[32];
    f32x4* const octA = smem;                   // oct coeffs d0..d3 (1208 slots)
    f32x4* const octB = smem + OASLOT;          // oct coeffs d4..d7
    f32x4* const tk   = smem;                   // main k tile (aliases, after barrier)

    const int tid  = threadIdx.x;
    const int lane = tid & 63;
    const int wid  = tid >> 6;
    const int b    = blockIdx.x;

    const float x1 = x1p[0];
    KC c;
    c.inv = 1.0f / x1; c.x1 = x1; c.x1sq = x1 * x1; c.x1_2 = 2.0f * x1;
    c.two_x1cu = 2.0f * x1 * c.x1sq; c.five_x1sq = 5.0f * c.x1sq;
    c.four_x1 = 4.0f * x1;
    const float gma = 64.0f / (6561.0f * c.x1sq * c.x1sq);   // perc = gma*s1^5
    const float cen = (184.0f / 350.0f) * x1;   // sigma domain center
    const float hw  = (208.0f / 350.0f) * x1;   // sigma domain half-width
    const float ihw = 1.0f / hw;

    float snode[8];
    {
        const float ND[8] = { CC1,  CC3,  CC5,  CC7, -CC7, -CC5, -CC3, -CC1};
        #pragma unroll
        for (int j = 0; j < 8; ++j) snode[j] = fmaf(hw, ND[j], cen);
    }
    // analytic coefficients for zero-input (padding) OCTS:
    //   sigma' = sigma - (8*gma/hw)*(hw*sigma+cen)^5   (exact to O(gma^2)~3e-5)
    f32x4 padA, padB;
    {
        const float qq = -8.0f * gma * ihw;
        const float c2_ = cen * cen, c3_ = c2_ * cen, c4_ = c2_ * c2_, c5_ = c4_ * cen;
        const float h2 = hw * hw, h3 = h2 * hw, h4 = h2 * h2, h5 = h4 * hw;
        padA = (f32x4){qq * c5_, fmaf(qq, 5.0f * hw * c4_, 1.0f),
                       qq * 10.0f * h2 * c3_, qq * 10.0f * h3 * c2_};
        padB = (f32x4){qq * 5.0f * h4 * cen, qq * h5, 0.0f, 0.0f};
    }

    // ---- phase 1a: build degree-7 OCT maps directly from x (all 4 waves) ----
    {
        const f32x4* __restrict__ x4 = (const f32x4*)x;  // one f32x4 == one PAIR
        const long Bb = (long)b * 4096 - (WUP / 2);      // pair idx of tile start
        const f32x4 z4 = (f32x4){0.f, 0.f, 0.f, 0.f};
        f32x4 w[4];
        {   // preload oct (m=0): Bb === 0 mod 4 => g<0 never straddles an oct
            const long g0 = Bb + 4L * tid;
            #pragma unroll
            for (int q = 0; q < 4; ++q)
                w[q] = (g0 >= 0) ? x4[g0 + q] : z4;
        }
        #pragma unroll 1
        for (int m = 0; m < 5; ++m) {                    // 5*256 >= 1192 octs
            const int o  = tid + (m << 8);
            const int o2 = o + 256;
            const long g2 = Bb + 4L * o2;
            f32x4 wn[4];
            #pragma unroll
            for (int q = 0; q < 4; ++q)                  // prefetch next oct
                wn[q] = (o2 < NOCTW && g2 >= 0) ? x4[g2 + q] : z4;
            if (o < NOCTW) {
                const long g = Bb + 4L * o;
                f32x4 ra, rb;
                if (g < 0) { ra = padA; rb = padB; }
                else {
                    float du0, du1;
                    f32x4 kk[8];
                    #pragma unroll
                    for (int q = 0; q < 4; ++q) {        // 8 exact per-step cubics
                        kk[2 * q]     = mkk(w[q].x, w[q].y, c, du0, du1);
                        kk[2 * q + 1] = mkk(w[q].z, w[q].w, c, du0, du1);
                    }
                    float v[8];
                    #pragma unroll
                    for (int j = 0; j < 8; ++j) {        // 8 independent node evals
                        float sv = snode[j];
                        #pragma unroll
                        for (int t2 = 0; t2 < 8; ++t2) stepk(sv, kk[t2], gma);
                        v[j] = (sv - cen) * ihw;
                    }
                    const float e0 = v[0] + v[7], e1 = v[1] + v[6];
                    const float e2 = v[2] + v[5], e3 = v[3] + v[4];
                    const float o0 = v[0] - v[7], o1 = v[1] - v[6];
                    const float o2v = v[2] - v[5], o3 = v[3] - v[4];
                    const float a0 = 0.125f * (e0 + e1 + e2 + e3);
                    const float a1 = 0.25f * (o0*CC1 + o1*CC3 + o2v*CC5 + o3*CC7);
                    const float a2 = 0.25f * ((e0 - e3)*CC2 + (e1 - e2)*CC6);
                    const float a3 = 0.25f * (o0*CC3 - o1*CC7 - o2v*CC1 - o3*CC5);
                    const float a4 = 0.25f * CC4 * ((e0 + e3) - (e1 + e2));
                    const float a5 = 0.25f * (o0*CC5 - o1*CC1 + o2v*CC7 + o3*CC3);
                    const float a6 = 0.25f * ((e0 - e3)*CC6 - (e1 - e2)*CC2);
                    const float a7 = 0.25f * (o0*CC7 - o1*CC5 + o2v*CC3 - o3*CC1);
                    ra = (f32x4){a0 - a2 + a4 - a6,
                                 a1 - 3.0f*a3 + 5.0f*a5 - 7.0f*a7,
                                 2.0f*a2 - 8.0f*a4 + 18.0f*a6,
                                 4.0f*a3 - 20.0f*a5 + 56.0f*a7};
                    rb = (f32x4){8.0f*a4 - 48.0f*a6,
                                 16.0f*a5 - 112.0f*a7,
                                 32.0f*a6,
                                 64.0f*a7};
                }
                const int slot = (o & 7) * NCO + (o >> 3);
                octA[slot] = ra;
                octB[slot] = rb;
            }
            #pragma unroll
            for (int q = 0; q < 4; ++q) w[q] = wn[q];
        }
    }
    __syncthreads();

    // ---- phase 2a: warm-up sigma-scan, 3 dep levels per OCT (lanes < 128) ---
    float aps = 0.f, apc = 0.f, qps = 0.f, qpc = 0.f;
    float sg = 0.f;
    if (tid < CPB) {
        const int l = tid;
        const long chk = (long)b * CPB + l;
        const float s0 = (chk * LCH >= WUP) ? 0.47f * x1 : 0.0f;
        sg = (s0 - cen) * ihw;
        f32x4 PA[8], PB[8], QA[8], QB[8];
        auto rdw = [&](f32x4 (&A)[8], f32x4 (&B)[8], const int st) {
            const int base = l + st;                     // oct o = 8*(l+st)+u
            #pragma unroll
            for (int u = 0; u < 8; ++u) A[u] = octA[base + u * NCO];
            #pragma unroll
            for (int u = 0; u < 8; ++u) B[u] = octB[base + u * NCO];
        };
        auto wstp = [&](f32x4 (&A)[8], f32x4 (&B)[8]) {
            #pragma unroll
            for (int u = 0; u < 8; ++u) {                // Estrin deg-7: 3 levels
                const float s2  = sg * sg;
                const float p0  = fmaf(A[u].y, sg, A[u].x);
                const float p1  = fmaf(A[u].w, sg, A[u].z);
                const float p2  = fmaf(B[u].y, sg, B[u].x);
                const float p3  = fmaf(B[u].w, sg, B[u].z);
                const float s4v = s2 * s2;
                const float q0  = fmaf(p1, s2, p0);
                const float q1  = fmaf(p3, s2, p2);
                sg = fmaf(q1, s4v, q0);
            }
        };
        rdw(PA, PB, 0);
        #pragma unroll 1
        for (int st = 0; st < WSTO; st += 2) {
            rdw(QA, QB, st + 1);
            wstp(PA, PB);
            rdw(PA, PB, st + 2);          // st+2 == WSTO on last iter: dead in-bounds read
            wstp(QA, QB);
        }
    }
    const float s_after = fmaf(hw, sg, cen);
    __syncthreads();

    // ---- phase 1b: re-stage exact main-step k's (all threads) + pn/en stats -
    float spn = 0.f, sen = 0.f, qpn = 0.f, qen = 0.f;
    {
        const f32x4* __restrict__ x4 = (const f32x4*)x;
        const long Fb = (long)b * 4096;
        f32x4 w = x4[Fb + tid];
        #pragma unroll 1
        for (int m = 0; m < 16; ++m) {
            const int f = tid + (m << 8);
            f32x4 wn = (m < 15) ? x4[Fb + f + 256] : w;   // prefetch
            #pragma unroll
            for (int h = 0; h < 2; ++h) {
                float pn, en;
                const f32x4 k = mkk(h ? w.z : w.x, h ? w.w : w.y, c, pn, en);
                const int t = 2 * f + h;
                tk[(t & 63) * NCK + (t >> 6)] = k;
                spn += pn; sen += en;
                qpn = fmaf(pn, pn, qpn); qen = fmaf(en, en, qen);
            }
            w = wn;
        }
    }
    __syncthreads();

    // ---- phase 2b: exact main scan with outputs (lanes < 128) ----
    if (tid < CPB) {
        const int l = tid;
        const size_t chunk = (size_t)b * CPB + l;
        float s = s_after;
        f32x4 KP[8], KQ[8];
        auto rdk = [&](f32x4 (&K)[8], const int m) {
            const int base = (m << 3) * NCK + l;
            #pragma unroll
            for (int u = 0; u < 8; ++u) K[u] = tk[base + u * NCK];
        };
        auto mst = [&](f32x4 (&K)[8], const int m) {
            float psv[8], pcv[8], sv[8];
            #pragma unroll
            for (int u = 0; u < 8; ++u) {
                stepk_m(s, K[u], gma, psv[u], pcv[u]);
                sv[u] = s;
            }
            #pragma unroll
            for (int u = 0; u < 8; ++u) {
                aps += psv[u]; apc += pcv[u];
                qps = fmaf(psv[u], psv[u], qps); qpc = fmaf(pcv[u], pcv[u], qpc);
            }
            const size_t pb = chunk * 32 + 4 * m;
            pspc4[pb + 0] = (f32x4){psv[0], pcv[0], psv[1], pcv[1]};
            pspc4[pb + 1] = (f32x4){psv[2], pcv[2], psv[3], pcv[3]};
            pspc4[pb + 2] = (f32x4){psv[4], pcv[4], psv[5], pcv[5]};
            pspc4[pb + 3] = (f32x4){psv[6], pcv[6], psv[7], pcv[7]};
            const size_t sb = chunk * 16 + 2 * m;
            s4[sb]     = (f32x4){sv[0], sv[1], sv[2], sv[3]};
            s4[sb + 1] = (f32x4){sv[4], sv[5], sv[6], sv[7]};
        };
        rdk(KP, 0);
        #pragma unroll 1
        for (int m = 0; m < NMST; m += 2) {
            rdk(KQ, m + 1);
            mst(KP, m);
            rdk(KP, m + 2 < NMST ? m + 2 : NMST - 1);     // clamped dead read
            mst(KQ, m + 1);
        }
    }

    // ---- block reduction of 8 stat accumulators ----
    float vals[8] = {spn, sen, aps, apc, qpn, qen, qps, qpc};
    #pragma unroll
    for (int k = 0; k < 8; ++k) {
        float v = vals[k];
        #pragma unroll
        for (int off = 32; off > 0; off >>= 1) v += __shfl_down(v, off, 64);
        if (lane == 0) red[k * 4 + wid] = v;
    }
    __syncthreads();
    if (tid < 8)
        partials[b * 8 + tid] =
            red[tid * 4] + red[tid * 4 + 1] + red[tid * 4 + 2] + red[tid * 4 + 3];
}

// ---- stats finalize folded in + fused normalize/assemble (unchanged) ----
__global__ __launch_bounds__(256) void normalize_stats(
        const float* __restrict__ x, const f32x4* __restrict__ pspc4,
        const float* __restrict__ pA, f32x4* __restrict__ out4,
        int nA, int Thalf, int T) {
    __shared__ float red[256];
    __shared__ float sst[8];
    const int tid = threadIdx.x;
    {   // components: 0 pn,1 en,2 ps,3 pc (sums); 4..7 squares
        const int c = tid & 7;
        float v = 0.f;
        for (int i = tid >> 3; i < nA; i += 32) v += pA[i * 8 + c];
        red[tid] = v;
        __syncthreads();
        for (int off = 128; off >= 8; off >>= 1) {
            if (tid < off) red[tid] += red[tid + off];
            __syncthreads();
        }
        if (tid == 0) {
            const float invT = 1.0f / (float)T;
            #pragma unroll
            for (int k = 0; k < 4; ++k) {
                float mu  = red[k] * invT;
                float var = fmaxf(fmaf(-mu, mu, red[4 + k] * invT), 0.0f);
                sst[k]     = mu;
                sst[4 + k] = (var > 0.0f) ? rsqrtf(var) : 0.0f;
            }
        }
        __syncthreads();
    }
    const float mu0 = sst[0], mu1 = sst[1], mu2 = sst[2], mu3 = sst[3];
    const float is0 = sst[4], is1 = sst[5], is2 = sst[6], is3 = sst[7];
    const f32x4* __restrict__ x4 = (const f32x4*)x;
    for (int i = blockIdx.x * 256 + tid; i < Thalf; i += 1024 * 256) {
        f32x4 xv = x4[i];
        f32x4 pq = pspc4[i];
        float d0 = xv.x - xv.y, d1 = xv.z - xv.w;
        out4[2 * i]     = (f32x4){(fmaxf(d0, 0.f) - mu0) * is0,
                                  (fmaxf(-d0, 0.f) - mu1) * is1,
                                  (pq.x - mu2) * is2,
                                  (pq.y - mu3) * is3};
        out4[2 * i + 1] = (f32x4){(fmaxf(d1, 0.f) - mu0) * is0,
                                  (fmaxf(-d1, 0.f) - mu1) * is1,
                                  (pq.z - mu2) * is2,
                                  (pq.w - mu3) * is3};
    }
}

// ---------------- round-1 fallback (proven; own WARMUP=2048, s0=0) ----------
#define L_CHUNK  128
#define FB_WARMUP 2048
__device__ __forceinline__ float inv1p_fb(float a) {
    float i1 = 1.0f - a;
    float i2 = fmaf(-a, i1, 1.0f);
    return fmaf(-a, i2, 1.0f);
}
struct SCfb { float x1, inv_x1, c49; };
__device__ __forceinline__ void scan_step_fb(float& s, float P, float E, const SCfb c,
                                             float& pn, float& en, float& ps, float& pc) {
    float d = P - E;
    float pn_ = fmaxf(d, 0.0f), en_ = fmaxf(-d, 0.0f);
    float up = pn_ * c.inv_x1;
    float tp = up * fmaf(up * up, -(1.0f / 3.0f), 1.0f);
    float un = en_ * c.inv_x1;
    float tn = un * fmaf(un * un, -(1.0f / 3.0f), 1.0f);
    float r = s * c.inv_x1;
    float ps_ = (tp * c.x1) * fmaf(-r, r, 1.0f) * inv1p_fb(r * tp);
    float es_ = (s * (2.0f - r)) * tn * inv1p_fb((1.0f - r) * tn);
    float s1 = s + ps_ - es_;
    float z = s1 * c.c49, z2 = z * z, v = z2 * z2;
    float t = fmaf(v, fmaf(v, 0.15625f, -0.25f), 1.0f);
    float s2 = s1 * t;
    pn = pn_; en = en_; ps = ps_; pc = s1 - s2; s = s2;
}
__global__ __launch_bounds__(256) void scan_kernel_fb(
        const float* __restrict__ x, const float* __restrict__ x1ptr,
        float* __restrict__ out, float* __restrict__ s_store,
        float* __restrict__ partials, int T) {
    const int c = blockIdx.x * blockDim.x + threadIdx.x;
    const int nchunks = (T + L_CHUNK - 1) / L_CHUNK;
    SCfb cc; cc.x1 = x1ptr[0]; cc.inv_x1 = 1.0f / cc.x1; cc.c49 = (4.0f / 9.0f) * cc.inv_x1;
    float s1a[4] = {0.f, 0.f, 0.f, 0.f};
    float s2a[4] = {0.f, 0.f, 0.f, 0.f};
    if (c < nchunks) {
        const int g0 = c * L_CHUNK;
        const int g1 = min(g0 + L_CHUNK, T);
        const int w0 = max(g0 - FB_WARMUP, 0);
        float s = 0.0f; float pn, en, ps, pc;
        const float2* __restrict__ x2 = (const float2*)x;
        for (int t = w0; t < g0; ++t) { float2 xv = x2[t]; scan_step_fb(s, xv.x, xv.y, cc, pn, en, ps, pc); }
        float4* __restrict__ out4 = (float4*)out;
        for (int t = g0; t < g1; ++t) {
            float2 xv = x2[t];
            scan_step_fb(s, xv.x, xv.y, cc, pn, en, ps, pc);
            out4[t] = make_float4(pn, en, ps, pc);
            s_store[t] = s;
            s1a[0] += pn; s1a[1] += en; s1a[2] += ps; s1a[3] += pc;
            s2a[0] = fmaf(pn, pn, s2a[0]); s2a[1] = fmaf(en, en, s2a[1]);
            s2a[2] = fmaf(ps, ps, s2a[2]); s2a[3] = fmaf(pc, pc, s2a[3]);
        }
    }
    __shared__ float red[256];
    float vals[8] = {s1a[0], s1a[1], s1a[2], s1a[3], s2a[0], s2a[1], s2a[2], s2a[3]};
    for (int k = 0; k < 8; ++k) {
        red[threadIdx.x] = vals[k];
        __syncthreads();
        for (int off = 128; off > 0; off >>= 1) {
            if ((int)threadIdx.x < off) red[threadIdx.x] += red[threadIdx.x + off];
            __syncthreads();
        }
        if (threadIdx.x == 0) partials[blockIdx.x * 8 + k] = red[0];
        __syncthreads();
    }
}
__global__ __launch_bounds__(64) void finalize_fb(
        const float* __restrict__ partials, float* __restrict__ stats, int nblk, int T) {
    const int lane = threadIdx.x;
    float v[8] = {0.f, 0.f, 0.f, 0.f, 0.f, 0.f, 0.f, 0.f};
    for (int b = lane; b < nblk; b += 64)
        for (int k = 0; k < 8; ++k) v[k] += partials[b * 8 + k];
    #pragma unroll
    for (int k = 0; k < 8; ++k)
        for (int off = 32; off > 0; off >>= 1) v[k] += __shfl_down(v[k], off, 64);
    if (lane == 0) {
        const float invT = 1.0f / (float)T;
        for (int k = 0; k < 4; ++k) {
            float mu = v[k] * invT;
            float var = fmaxf(fmaf(-mu, mu, v[k + 4] * invT), 0.0f);
            stats[k] = mu;
            stats[4 + k] = (var > 0.0f) ? rsqrtf(var) : 0.0f;
        }
    }
}
__global__ __launch_bounds__(256) void normalize_fb(
        float* __restrict__ out, const float* __restrict__ stats, int T) {
    const int t = blockIdx.x * blockDim.x + threadIdx.x;
    if (t >= T) return;
    const float4 mu = *(const float4*)stats;
    const float4 is = *(const float4*)(stats + 4);
    float4* o4 = (float4*)out;
    float4 v = o4[t];
    v.x = (v.x - mu.x) * is.x; v.y = (v.y - mu.y) * is.y;
    v.z = (v.z - mu.z) * is.z; v.w = (v.w - mu.w) * is.w;
    o4[t] = v;
}
// -----------------------------------------------------------------------------

extern "C" void kernel_launch(void* const* d_in, const int* in_sizes, int n_in,
                              void* d_out, int out_size, void* d_ws, size_t ws_size,
                              hipStream_t stream) {
    const float* x  = (const float*)d_in[0];
    const float* x1 = (const float*)d_in[1];
    const int T = in_sizes[0] / 2;

    float* out     = (float*)d_out;                // (T,4)
    float* s_store = out + 4 * (size_t)T;          // (T,)

    const int nblk = T / BSTEPS;                   // scan blocks (fast path)

    float* pA = (float*)d_ws;                      // nblk*8 floats (<=2048)
    const size_t pq_off = 2048;                    // f32x4-aligned float offset
    const size_t need = (pq_off + 2 * (size_t)T) * sizeof(float);

    const bool fast = (T % BSTEPS == 0) && nblk >= 1 && nblk <= 256 &&
                      (ws_size >= need);

    if (fast) {
        f32x4* pspc4 = (f32x4*)((float*)d_ws + pq_off);
        scan_oct<<<nblk, TPB, 0, stream>>>(x, x1, pspc4, (f32x4*)s_store, pA);
        normalize_stats<<<1024, 256, 0, stream>>>(x, pspc4, pA,
                                                  (f32x4*)out, nblk, T / 2, T);
    } else {
        float* stats    = (float*)d_ws;
        float* partials = stats + 8;
        const int nchunks = (T + L_CHUNK - 1) / L_CHUNK;
        const int nblkA = (nchunks + 255) / 256;
        scan_kernel_fb<<<nblkA, 256, 0, stream>>>(x, x1, out, s_store, partials, T);
        finalize_fb<<<1, 64, 0, stream>>>(partials, stats, nblkA, T);
        normalize_fb<<<(T + 255) / 256, 256, 0, stream>>>(out, stats, T);
    }
}